// Round 15
// baseline (85.599 us; speedup 1.0000x reference)
//
#include <hip/hip_runtime.h>
#include <hip/hip_bf16.h>

#define D_NODE 16
#define D_EDGE 8
#define D_IN   40
#define D_HID  64
#define NG     500
#define TPB    256

typedef __attribute__((ext_vector_type(8))) short bf16x8;
typedef __attribute__((ext_vector_type(4))) short bf16x4;
typedef __attribute__((ext_vector_type(4))) float f32x4;

__device__ __forceinline__ short f2bf(float f) {
    union { __hip_bfloat16 h; short s; } u;
    u.h = __float2bfloat16(f);   // RNE
    return u.s;
}

// Packed RNE bf16 pair via HIP intrinsic (compiler-lowered, no inline asm).
__device__ __forceinline__ int pk2(float lo, float hi) {
    union { __hip_bfloat162 h; int i; } u;
    u.h = __float22bfloat162_rn(make_float2(lo, hi));   // low word = lo
    return u.i;
}

#if __has_builtin(__builtin_amdgcn_mfma_f32_16x16x16bf16_1k)
#define MFMA16(A, B, C) __builtin_amdgcn_mfma_f32_16x16x16bf16_1k(A, B, C, 0, 0, 0)
#else
static __device__ __forceinline__ f32x4 mfma16_asm(bf16x4 a, bf16x4 b, f32x4 c) {
    asm volatile("v_mfma_f32_16x16x16_bf16 %0, %1, %2, %0"
                 : "+v"(c) : "v"(a), "v"(b));
    return c;
}
#define MFMA16(A, B, C) mfma16_asm(A, B, C)
#endif

// r14's verified MFMA chain, with the LDS staging round-trip REMOVED:
// the 16x16x32 B-fragment layout (lane(q,r15) holds m[e=r15][k=8q..8q+7])
// maps 1:1 onto per-lane 32B gathers from x (q0/q1 = dst halves, q2/q3 =
// src halves); bm1 = ea[e][0..7] in q0 lanes (feats 32..39) + zeros.
// No mbuf, no ds_write/ds_read, no lgkmcnt(0) drains. Weights in registers
// (r14-verified with f2bf-hb), biases in tiny LDS tables, 2-slot ping-pong
// with idx prefetched one phase ahead of the x-gather.
__global__ __launch_bounds__(TPB) void mof_mfma13(
    const float* __restrict__ x, const float* __restrict__ ea,
    const float* __restrict__ W1, const float* __restrict__ b1,
    const float* __restrict__ W2, const float* __restrict__ b2,
    const float* __restrict__ W3, const float* __restrict__ b3,
    const int* __restrict__ ei, const int* __restrict__ batch,
    float* __restrict__ out, int E)
{
    __shared__ __align__(16) float sh_b1[D_HID];
    __shared__ __align__(16) float sh_b2[D_HID];
    __shared__ __align__(16) float sh_w3[D_HID];
    __shared__ float gacc[NG];

    for (int i = threadIdx.x; i < D_HID; i += TPB) {
        sh_b1[i] = b1[i];
        sh_b2[i] = b2[i];
        sh_w3[i] = W3[i];
    }
    for (int g = threadIdx.x; g < NG; g += TPB) gacc[g] = 0.f;
    __syncthreads();

    const int lane = threadIdx.x & 63;
    const int q    = lane >> 4;    // quarter-wave 0..3
    const int r15  = lane & 15;
    const int qlt2 = (q < 2);

    // ---- per-lane W1 fragments in registers (verbatim r14) ----
    bf16x8 w1f[2][4];
    #pragma unroll
    for (int kb = 0; kb < 2; ++kb)
        #pragma unroll
        for (int nb = 0; nb < 4; ++nb)
            #pragma unroll
            for (int j = 0; j < 8; ++j) {
                const int k = kb * 32 + q * 8 + j;
                const int n = nb * 16 + r15;
                w1f[kb][nb][j] = (k < D_IN) ? f2bf(W1[k * D_HID + n]) : (short)0;
            }
    // ---- per-lane W2 fragments in registers (verbatim r14) ----
    bf16x4 a2f[4][4];
    #pragma unroll
    for (int kb = 0; kb < 4; ++kb)
        #pragma unroll
        for (int nb = 0; nb < 4; ++nb)
            #pragma unroll
            for (int j = 0; j < 4; ++j) {
                const int k = kb * 16 + q * 4 + j;
                const int n = nb * 16 + r15;
                a2f[kb][nb][j] = f2bf(W2[k * D_HID + n]);
            }
    const float b3v = b3[0];

    const int ntiles = (E + 15) >> 4;
    const int wid = (blockIdx.x * TPB + threadIdx.x) >> 6;
    const int nw  = (gridDim.x * TPB) >> 6;

    // this lane's node index for tile t: q<2 -> dst of edge base+r15,
    // q>=2 -> src (clamped; q0's value is also the scatter dst node)
    auto ld_idx = [&](int t) -> int {
        int tb = t < ntiles ? t : ntiles - 1;
        int e4 = (tb << 4) + r15; if (e4 >= E) e4 = E - 1;
        return ei[(qlt2 ? E : 0) + e4];
    };
    // 32B x-gather per lane (the B-fragment slice) + 32B ea in q0 lanes
    auto ld_x = [&](int t, int idx, float4& xa, float4& xb, float4& ea0, float4& ea1) {
        const float* xp = x + (size_t)idx * D_NODE + (q & 1) * 8;
        xa = *reinterpret_cast<const float4*>(xp);
        xb = *reinterpret_cast<const float4*>(xp + 4);
        if (q == 0) {
            int tb = t < ntiles ? t : ntiles - 1;
            int e4 = (tb << 4) + r15; if (e4 >= E) e4 = E - 1;
            const float* ep = ea + (size_t)e4 * D_EDGE;
            ea0 = *reinterpret_cast<const float4*>(ep);
            ea1 = *reinterpret_cast<const float4*>(ep + 4);
        }
    };
    // pack B-fragments in-register + r14's verbatim MFMA chain / epilogue
    auto compute_tile = [&](const float4& xa, const float4& xb,
                            const float4& ea0, const float4& ea1,
                            int tbase, int g) {
        union { bf16x8 v; int i[4]; } u0;
        u0.i[0] = pk2(xa.x, xa.y); u0.i[1] = pk2(xa.z, xa.w);
        u0.i[2] = pk2(xb.x, xb.y); u0.i[3] = pk2(xb.z, xb.w);
        const bf16x8 bm0 = u0.v;
        union { bf16x8 v; int i[4]; } u1;
        u1.i[0] = 0; u1.i[1] = 0; u1.i[2] = 0; u1.i[3] = 0;
        if (q == 0) {
            u1.i[0] = pk2(ea0.x, ea0.y); u1.i[1] = pk2(ea0.z, ea0.w);
            u1.i[2] = pk2(ea1.x, ea1.y); u1.i[3] = pk2(ea1.z, ea1.w);
        }
        const bf16x8 bm1 = u1.v;

        f32x4 acc1[4];
        #pragma unroll
        for (int nb = 0; nb < 4; ++nb)
            acc1[nb] = *reinterpret_cast<const f32x4*>(&sh_b1[nb * 16 + q * 4]);
        #pragma unroll
        for (int nb = 0; nb < 4; ++nb) {
            acc1[nb] = __builtin_amdgcn_mfma_f32_16x16x32_bf16(w1f[0][nb], bm0, acc1[nb], 0, 0, 0);
            acc1[nb] = __builtin_amdgcn_mfma_f32_16x16x32_bf16(w1f[1][nb], bm1, acc1[nb], 0, 0, 0);
        }
        f32x4 acc2[4];
        #pragma unroll
        for (int nb = 0; nb < 4; ++nb)
            acc2[nb] = *reinterpret_cast<const f32x4*>(&sh_b2[nb * 16 + q * 4]);
        #pragma unroll
        for (int kb = 0; kb < 4; ++kb) {
            bf16x4 hb;
            #pragma unroll
            for (int j = 0; j < 4; ++j)
                hb[j] = f2bf(fmaxf(acc1[kb][j], 0.f));
            #pragma unroll
            for (int nb = 0; nb < 4; ++nb)
                acc2[nb] = MFMA16(a2f[kb][nb], hb, acc2[nb]);
        }
        float msg = 0.f;
        #pragma unroll
        for (int nb = 0; nb < 4; ++nb) {
            const f32x4 w3 = *reinterpret_cast<const f32x4*>(&sh_w3[nb * 16 + q * 4]);
            #pragma unroll
            for (int rr = 0; rr < 4; ++rr)
                msg = fmaf(fmaxf(acc2[nb][rr], 0.f), w3[rr], msg);
        }
        msg += __shfl_xor(msg, 16);
        msg += __shfl_xor(msg, 32);
        const int e = tbase + r15;
        if (q == 0 && e < E) atomicAdd(&gacc[g], msg + b3v);
    };

    if (wid < ntiles) {
        float4 xaA, xbA, eaA0 = {0,0,0,0}, eaA1 = {0,0,0,0};
        float4 xaB, xbB, eaB0 = {0,0,0,0}, eaB1 = {0,0,0,0};

        int t  = wid;
        int iA = ld_idx(t);
        ld_x(t, iA, xaA, xbA, eaA0, eaA1);
        int gA = batch[iA];
        int iB = ld_idx(t + nw);

        for (;;) {
            const int tn = t + nw;
            ld_x(tn, iB, xaB, xbB, eaB0, eaB1);   // slot B loads fly over compute A
            int gB = batch[iB];
            iA = ld_idx(tn + nw);                 // idx one phase ahead of its gather
            compute_tile(xaA, xbA, eaA0, eaA1, t << 4, gA);
            if (tn >= ntiles) break;

            const int tnn = tn + nw;
            ld_x(tnn, iA, xaA, xbA, eaA0, eaA1);
            gA = batch[iA];
            iB = ld_idx(tnn + nw);
            compute_tile(xaB, xbB, eaB0, eaB1, tn << 4, gB);
            if (tnn >= ntiles) break;
            t = tnn;
        }
    }

    __syncthreads();
    for (int g = threadIdx.x; g < NG; g += TPB) {
        const float v = gacc[g];
        if (v != 0.f) atomicAdd(&out[g], 0.5f * v);
    }
}

extern "C" void kernel_launch(void* const* d_in, const int* in_sizes, int n_in,
                              void* d_out, int out_size, void* d_ws, size_t ws_size,
                              hipStream_t stream) {
    const float* x  = (const float*)d_in[0];
    const float* ea = (const float*)d_in[1];
    const float* W1 = (const float*)d_in[2];
    const float* b1 = (const float*)d_in[3];
    const float* W2 = (const float*)d_in[4];
    const float* b2 = (const float*)d_in[5];
    const float* W3 = (const float*)d_in[6];
    const float* b3 = (const float*)d_in[7];
    const int*   ei    = (const int*)d_in[8];
    const int*   batch = (const int*)d_in[9];
    float* out = (float*)d_out;

    const int E = in_sizes[1] / D_EDGE;

    hipMemsetAsync(d_out, 0, (size_t)out_size * sizeof(float), stream);

    const int blocks = 1024;   // 4096 waves; LDS ~4.6KB (no staging buffers)
    mof_mfma13<<<blocks, TPB, 0, stream>>>(x, ea, W1, b1, W2, b2, W3, b3,
                                           ei, batch, out, E);
}